// Round 8
// baseline (542.212 us; speedup 1.0000x reference)
//
#include <hip/hip_runtime.h>
#include <math.h>

// Problem constants
#define kH  1024
#define kB  64
#define kS  256
#define kV  10000
#define kH3 3072

typedef unsigned long long u64;

// ---------------- helpers ----------------
__device__ __forceinline__ float warp_sum(float v) {
#pragma unroll
  for (int off = 32; off > 0; off >>= 1) v += __shfl_down(v, off, 64);
  return v;  // valid on lane 0
}
__device__ __forceinline__ float warp_max_all(float v) {
#pragma unroll
  for (int off = 32; off > 0; off >>= 1) v = fmaxf(v, __shfl_xor(v, off, 64));
  return v;
}
__device__ __forceinline__ float warp_sum_all(float v) {
#pragma unroll
  for (int off = 32; off > 0; off >>= 1) v += __shfl_xor(v, off, 64);
  return v;
}
__device__ __forceinline__ float sigmoidf_(float x) {
  return __fdividef(1.0f, 1.0f + __expf(-x));
}
__device__ __forceinline__ float tanhf_(float x) {
  const float t = __expf(-2.0f * fabsf(x));
  const float r = __fdividef(1.0f - t, 1.0f + t);
  return copysignf(r, x);
}

// ======= Launch A: gi-GEMM (192 blocks) || w2h (256 blocks) ==============
// R8 gi rewrite: the old gi (carried since R0) was ~150 us — 3072 waves x
// 64 t, each re-reading the same 4 KB emb row (786 MB L2 broadcast) and
// doing an 18-op shuffle reduction per output scalar. New gi is a tiled
// GEMM: block owns a 64t x 16r tile of GI = emb[seq] @ W_ih^T; per 64-h
// chunk, X staged transposed [h][t+pad] (conflict-free scalar reads,
// lane = t) and W staged [r][h] (wave-uniform broadcast b128 reads);
// 4 accumulators per thread, sequential-h order (deterministic). No
// shuffles, X read once per block (49 MB total L2 traffic vs 786 MB).
//
// w2h: w2h[k] = sum_h v_attn[h] * W_attn[h][H+k]  (softmax shift-invariance
//      kills the h_bc half of cat and b_attn)
__global__ __launch_bounds__(256) void k_pre(const int* __restrict__ seq,
    const float* __restrict__ emb, const float* __restrict__ W_ih,
    const float* __restrict__ b_ih, const float* __restrict__ W_attn,
    const float* __restrict__ v_attn, float* __restrict__ GI,
    float* __restrict__ w2h) {
  __shared__ float xl[64 * 65];   // X chunk, transposed [h][t], pad 65
  __shared__ float wl[16 * 64];   // W chunk, [r][h]
  __shared__ float4 red[256];     // w2h reduction
  const int tid = threadIdx.x;

  if (blockIdx.x < 192) {
    // ---- gi role ----
    const int rblk = blockIdx.x * 16;
    const int t = tid & 63;       // lane = t (batch index)
    const int g = tid >> 6;       // wave = r-group (4 rows each)
    float acc[4] = {0.f, 0.f, 0.f, 0.f};

    for (int c = 0; c < 16; ++c) {
      const int h0 = c * 64;
      // stage X: thread (tx = tid>>2) covers 4 float4 slots of its row
      {
        const int tx = tid >> 2;
        const int tok = seq[tx];
        const float* xr = emb + (size_t)tok * kH + h0;
#pragma unroll
        for (int k = 0; k < 4; ++k) {
          const int slot = (tid & 3) + 4 * k;    // 0..15
          const float4 v = *(const float4*)(xr + slot * 4);
          const int hh = slot * 4;
          xl[(hh + 0) * 65 + tx] = v.x;
          xl[(hh + 1) * 65 + tx] = v.y;
          xl[(hh + 2) * 65 + tx] = v.z;
          xl[(hh + 3) * 65 + tx] = v.w;
        }
      }
      // stage W: 16 rows x 64 h = 256 float4, one per thread (coalesced)
      {
        const int r = tid >> 4, c4 = tid & 15;
        *(float4*)&wl[r * 64 + c4 * 4] =
            ((const float4*)(W_ih + (size_t)(rblk + r) * kH + h0))[c4];
      }
      __syncthreads();
#pragma unroll
      for (int q = 0; q < 16; ++q) {
        const int hh = q * 4;
        const float x0 = xl[(hh + 0) * 65 + t];
        const float x1 = xl[(hh + 1) * 65 + t];
        const float x2 = xl[(hh + 2) * 65 + t];
        const float x3 = xl[(hh + 3) * 65 + t];
#pragma unroll
        for (int i = 0; i < 4; ++i) {
          const float4 wq = *(const float4*)&wl[(g * 4 + i) * 64 + hh];
          acc[i] += wq.x * x0 + wq.y * x1 + wq.z * x2 + wq.w * x3;
        }
      }
      __syncthreads();
    }
    const float4 bi = *(const float4*)(b_ih + rblk + g * 4);
    float4 o;
    o.x = acc[0] + bi.x; o.y = acc[1] + bi.y;
    o.z = acc[2] + bi.z; o.w = acc[3] + bi.w;
    *(float4*)(GI + (size_t)t * kH3 + rblk + g * 4) = o;

  } else {
    // ---- w2h role ----
    const int wb = blockIdx.x - 192;
    const int k0 = kH + wb * 4;  // absolute column in W_attn
    float ax = 0, ay = 0, az = 0, aw = 0;
    for (int h = tid; h < kH; h += 256) {
      const float vh = v_attn[h];
      const float4 wq = *(const float4*)(W_attn + (size_t)h * 2048 + k0);
      ax += vh * wq.x; ay += vh * wq.y; az += vh * wq.z; aw += vh * wq.w;
    }
    red[tid] = make_float4(ax, ay, az, aw);
    __syncthreads();
    for (int s = 128; s > 0; s >>= 1) {
      if (tid < s) {
        const float4 a = red[tid], b = red[tid + s];
        red[tid] = make_float4(a.x + b.x, a.y + b.y, a.z + b.z, a.w + b.w);
      }
      __syncthreads();
    }
    if (tid == 0) *(float4*)(w2h + wb * 4) = red[0];
  }
}

// ---------------- Persistent GRU scan (64 sequential steps) ----------------
// R5 structure, byte-identical (R6's mega fusion regressed 2x: co-resident
// polling waves hammered the STEP lines and inflated the serial exchange
// RTT — reverted). 256 blocks x 256 threads, one block per CU. Block bid
// owns h[4*bid..4*bid+3]; wave w owns element j = 4*bid + w. W_hh rows in
// LDS (48 KB; regalloc refuses register residency — R1-R3 evidence).
// Handshake: relaxed agent-scope u64 atomics (tag t+1 | float bits);
// ws poison 0xAAAAAAAA never matches tags 1..64.
__global__ __launch_bounds__(256) void k_gru(const float* __restrict__ h0,
    const float* __restrict__ W_hh, const float* __restrict__ b_hh,
    const float* __restrict__ GI, float* __restrict__ rnn,
    u64* __restrict__ step) {
  __shared__ float4 wlds4[12 * 256];      // 48 KB: 12 rows (3 gates x 4 elems)
  __shared__ __align__(16) float hs[2][kH];  // 8 KB double buffer
  const int tid  = threadIdx.x;           // 0..255
  const int lane = tid & 63;
  const int w    = tid >> 6;              // 0..3
  const int bid  = blockIdx.x;            // 0..255
  const int j    = bid * 4 + w;           // output element owned by this wave

  // ---- stage 12 W_hh rows into LDS (coalesced float4, conflict-free) ----
#pragma unroll
  for (int c = 0; c < 12; ++c) {
    const int f    = c * 256 + tid;       // 0..3071
    const int row  = f >> 8;              // 0..11
    const int col4 = f & 255;             // 0..255
    const int q    = row >> 2, r = row & 3;
    wlds4[f] = ((const float4*)(W_hh + ((size_t)q * kH + bid * 4 + r) * kH))[col4];
  }

  const float bhr = b_hh[j];
  const float bhz = b_hh[kH + j];
  const float bhn = b_hh[2 * kH + j];

  for (int t = 0; t < kB; ++t) {
    // ---- prefetch GI[t] (h-independent): latency hides under the poll ----
    float gir = GI[(size_t)t * kH3 + j];
    float giz = GI[(size_t)t * kH3 + kH + j];
    float gin = GI[(size_t)t * kH3 + 2 * kH + j];
    asm volatile("" :: "v"(gir), "v"(giz), "v"(gin));

    float* hb = hs[t & 1];
    // ---- stage h_prev into LDS (4 slots per thread) ----
    if (t == 0) {
      ((float4*)hb)[tid] = ((const float4*)h0)[tid];
    } else {
      const u64* sb = step + (size_t)(t - 1) * kH;
      const unsigned want = (unsigned)t;  // producer of step t-1 wrote tag t
      const int i0 = tid * 4;
      bool done[4] = {false, false, false, false};
      float v[4];
      while (true) {
        bool all = true;
#pragma unroll
        for (int k = 0; k < 4; ++k) {
          if (!done[k]) {
            const u64 x = __hip_atomic_load(&sb[i0 + k],
                __ATOMIC_RELAXED, __HIP_MEMORY_SCOPE_AGENT);
            if ((unsigned)(x >> 32) == want) {
              v[k] = __uint_as_float((unsigned)x);
              done[k] = true;
            } else {
              all = false;
            }
          }
        }
        if (all) break;
        __builtin_amdgcn_s_sleep(1);
      }
#pragma unroll
      for (int k = 0; k < 4; ++k) hb[i0 + k] = v[k];
    }
    __syncthreads();  // also orders the one-time weight ds_writes at t==0

    // ---- hx4[c] = h_prev float4 slice (conflict-free b128 reads) ----
    float4 hx4[4];
#pragma unroll
    for (int c = 0; c < 4; ++c) hx4[c] = ((const float4*)hb)[lane + 64 * c];

    // ---- d[q] = W_hh[q*kH+j][:] . h_prev  (weights from LDS) ----
    float d[3];
#pragma unroll
    for (int q = 0; q < 3; ++q) {
      float acc = 0.f;
#pragma unroll
      for (int c = 0; c < 4; ++c) {
        const float4 wq = wlds4[(q * 4 + w) * 256 + lane + 64 * c];
        const float4 h4 = hx4[c];
        acc += wq.x * h4.x + wq.y * h4.y + wq.z * h4.z + wq.w * h4.w;
      }
      d[q] = acc;
    }
#pragma unroll
    for (int q = 0; q < 3; ++q) d[q] = warp_sum(d[q]);

    if (lane == 0) {
      const float ho = hb[j];  // exact h_prev from LDS
      const float r = sigmoidf_(gir + d[0] + bhr);
      const float z = sigmoidf_(giz + d[1] + bhz);
      const float n = tanhf_(gin + r * (d[2] + bhn));
      const float hn = (1.f - z) * n + z * ho;
      rnn[(size_t)t * kH + j] = hn;  // for downstream kernels
      __hip_atomic_store(&step[(size_t)t * kH + j],
                         (((u64)(t + 1)) << 32) | __float_as_uint(hn),
                         __ATOMIC_RELAXED, __HIP_MEMORY_SCOPE_AGENT);
    }
    // no trailing barrier: double-buffered hs (see R5 analysis)
  }
}

// ========== Launch C: fused scores + softmax + context + hid =============
// 64 blocks (one per b) x 1024 threads (16 waves). Block b computes its own
// 256 scores (wave w does s = w*16..w*16+15; dot order bit-identical to the
// old k_scores), then softmax and context (bit-identical to R5's k_ctx2).
__global__ __launch_bounds__(1024) void k_att(const float* __restrict__ enc,
    const float* __restrict__ w2h, const float* __restrict__ rnn,
    float* __restrict__ attn, float* __restrict__ ctx,
    float* __restrict__ hid) {
  __shared__ float scl[kS];
  __shared__ float sm[4], ss[4];
  __shared__ float4 part4[1024];  // 16 KB
  const int b = blockIdx.x, tid = threadIdx.x;
  const int lane = tid & 63, w = tid >> 6;  // w: 0..15

  // ---- Phase 1: scores ----
  {
    const float4* wp = (const float4*)w2h + lane * 4;
    const float4 wq0 = wp[0], wq1 = wp[1], wq2 = wp[2], wq3 = wp[3];
    for (int k = 0; k < 16; ++k) {
      const int s = w * 16 + k;
      const float4* ep =
          (const float4*)(enc + ((size_t)s * kB + b) * kH) + lane * 4;
      const float4 e0 = ep[0], e1 = ep[1], e2 = ep[2], e3 = ep[3];
      float acc = e0.x*wq0.x + e0.y*wq0.y + e0.z*wq0.z + e0.w*wq0.w;
      acc += e1.x*wq1.x + e1.y*wq1.y + e1.z*wq1.z + e1.w*wq1.w;
      acc += e2.x*wq2.x + e2.y*wq2.y + e2.z*wq2.z + e2.w*wq2.w;
      acc += e3.x*wq3.x + e3.y*wq3.y + e3.z*wq3.z + e3.w*wq3.w;
      acc = warp_sum(acc);
      if (lane == 0) scl[s] = acc;
    }
  }
  __syncthreads();

  // ---- Phase 2: softmax over 256 scores (waves 0..3 only) ----
  float x = 0.f, e = 0.f;
  if (tid < kS) {
    x = scl[tid];
    const float m = warp_max_all(x);
    if (lane == 0) sm[w] = m;
  }
  __syncthreads();
  if (tid < kS) {
    const float m = fmaxf(fmaxf(sm[0], sm[1]), fmaxf(sm[2], sm[3]));
    e = __expf(x - m);
    const float s = warp_sum_all(e);
    if (lane == 0) ss[w] = s;
  }
  __syncthreads();
  if (tid < kS) {
    const float s = ss[0] + ss[1] + ss[2] + ss[3];
    const float a = e / s;
    attn[b * kS + tid] = a;   // output (B,1,S)
    scl[tid] = a;             // reuse as weight array
  }
  if (b < 4 && tid < kS) {    // hidden output copy (independent)
    hid[b * kS + tid] = rnn[63 * kH + b * kS + tid];
  }
  __syncthreads();

  // ---- Phase 3: context; thread owns h-chunk hc within s-quarter sq ----
  const int hc = tid & 255;
  const int sq = tid >> 8;    // 0..3
  const float4* encb = (const float4*)enc;
  float4 acc = make_float4(0.f, 0.f, 0.f, 0.f);
  const int s0 = sq * 64;
#pragma unroll 4
  for (int s = s0; s < s0 + 64; ++s) {
    const float a = scl[s];
    const float4 v = encb[((size_t)s * kB + b) * 256 + hc];
    acc.x += a * v.x; acc.y += a * v.y; acc.z += a * v.z; acc.w += a * v.w;
  }
  part4[tid] = acc;
  __syncthreads();
  if (tid < 256) {
    const float4 p0 = part4[tid], p1 = part4[tid + 256];
    const float4 p2 = part4[tid + 512], p3 = part4[tid + 768];
    float4 r;
    r.x = p0.x + p1.x + p2.x + p3.x;
    r.y = p0.y + p1.y + p2.y + p3.y;
    r.z = p0.z + p1.z + p2.z + p3.z;
    r.w = p0.w + p1.w + p2.w + p3.w;
    ((float4*)(ctx + (size_t)b * kH))[tid] = r;
  }
}

// ---------------- coT[i][b] = tanh([rnn,ctx][b] . W_concat[i] + b_c[i]) ----------------
// b-loop split 4 ways (1024 blocks) for TLP; W_c rows re-read 4x (L2).
__global__ __launch_bounds__(256) void k_concat(const float* __restrict__ rnn,
    const float* __restrict__ ctx, const float* __restrict__ W_c,
    const float* __restrict__ b_c, float* __restrict__ coT) {
  const int lane = threadIdx.x & 63;
  const int iq = blockIdx.x >> 2;                 // 0..255
  const int bq = blockIdx.x & 3;                  // 0..3
  const int i  = iq * 4 + (threadIdx.x >> 6);     // 0..1023
  float wreg[32];
  {
    const float4* wp = (const float4*)(W_c + (size_t)i * 2048) + lane * 8;
#pragma unroll
    for (int c = 0; c < 8; ++c) {
      const float4 f = wp[c];
      wreg[c * 4 + 0] = f.x; wreg[c * 4 + 1] = f.y;
      wreg[c * 4 + 2] = f.z; wreg[c * 4 + 3] = f.w;
    }
  }
  const float bc = b_c[i];
  const int jcol = lane * 32;
  const float* xbase = (jcol < kH) ? (rnn + jcol) : (ctx + (jcol - kH));
  for (int b = bq * 16; b < bq * 16 + 16; ++b) {
    const float* xr = xbase + (size_t)b * kH;
    float acc = 0.f;
#pragma unroll
    for (int c = 0; c < 8; ++c) {
      const float4 x = *(const float4*)(xr + c * 4);
      acc += wreg[c * 4 + 0] * x.x + wreg[c * 4 + 1] * x.y +
             wreg[c * 4 + 2] * x.z + wreg[c * 4 + 3] * x.w;
    }
    acc = warp_sum(acc);
    if (lane == 0) coT[(size_t)i * kB + b] = tanhf(acc + bc);
  }
}

// ---------------- out[b][v] = coT[:,b] . W_out[v] + b_out[v] ----------------
// 625 blocks x 256 threads; stage 16 W_out rows (64 KB) in LDS with 16
// outstanding coalesced float4 loads/thread; lane=b; broadcast LDS W reads.
__global__ __launch_bounds__(256) void k_out(const float* __restrict__ coT,
    const float* __restrict__ W_out, const float* __restrict__ b_out,
    float* __restrict__ out) {
  __shared__ float wlds[16 * kH];  // 64 KB
  const int v0 = blockIdx.x * 16;
  {
    const float4* src = (const float4*)(W_out + (size_t)v0 * kH);
    float4 tmp[16];
#pragma unroll
    for (int c = 0; c < 16; ++c) tmp[c] = src[threadIdx.x + 256 * c];
    float4* dst = (float4*)wlds;
#pragma unroll
    for (int c = 0; c < 16; ++c) dst[threadIdx.x + 256 * c] = tmp[c];
  }
  __syncthreads();

  const int lane = threadIdx.x & 63;   // = b
  const int w    = threadIdx.x >> 6;   // wave: v-rows 4w..4w+3
  float acc[4] = {0.f, 0.f, 0.f, 0.f};
#pragma unroll 2
  for (int h = 0; h < kH; h += 4) {
    const float x0 = coT[(size_t)(h + 0) * kB + lane];
    const float x1 = coT[(size_t)(h + 1) * kB + lane];
    const float x2 = coT[(size_t)(h + 2) * kB + lane];
    const float x3 = coT[(size_t)(h + 3) * kB + lane];
#pragma unroll
    for (int vi = 0; vi < 4; ++vi) {
      const float4 wq = *(const float4*)&wlds[(w * 4 + vi) * kH + h];
      acc[vi] += wq.x * x0 + wq.y * x1 + wq.z * x2 + wq.w * x3;
    }
  }
  const float4 bq = *(const float4*)(b_out + v0 + w * 4);
  float4 r;
  r.x = acc[0] + bq.x; r.y = acc[1] + bq.y;
  r.z = acc[2] + bq.z; r.w = acc[3] + bq.w;
  *(float4*)&out[(size_t)lane * kV + v0 + w * 4] = r;
}

// ---------------- launcher ----------------
extern "C" void kernel_launch(void* const* d_in, const int* in_sizes, int n_in,
                              void* d_out, int out_size, void* d_ws,
                              size_t ws_size, hipStream_t stream) {
  const int*   seq    = (const int*)  d_in[0];
  const float* h0     = (const float*)d_in[1];
  const float* enc    = (const float*)d_in[2];
  const float* emb    = (const float*)d_in[3];
  const float* W_ih   = (const float*)d_in[4];
  const float* W_hh   = (const float*)d_in[5];
  const float* b_ih   = (const float*)d_in[6];
  const float* b_hh   = (const float*)d_in[7];
  const float* W_attn = (const float*)d_in[8];
  // d_in[9] = b_attn: drops out of softmax (shift invariance)
  const float* v_attn = (const float*)d_in[10];
  const float* W_conc = (const float*)d_in[11];
  const float* b_conc = (const float*)d_in[12];
  const float* W_outp = (const float*)d_in[13];
  const float* b_outp = (const float*)d_in[14];

  float* out      = (float*)d_out;           // (B,V) = 640000
  float* out_hid  = out + 640000;            // (1,1,H) = 1024
  float* out_attn = out + 641024;            // (B,1,S) = 16384

  float* ws = (float*)d_ws;
  float* GI   = ws;                      // 64*3072     = 196608
  float* RNN  = ws + 196608;             // 64*1024     =  65536
  u64*   STEP = (u64*)(ws + 262144);     // 64*1024 u64 = 131072 floats
  float* W2H  = ws + 393216;             // 1024
  float* CTX  = ws + 394240;             // 64*1024     =  65536
  float* COT  = ws + 459776;             // 1024*64     =  65536 (end 525312)

  k_pre<<<448, 256, 0, stream>>>(seq, emb, W_ih, b_ih, W_attn, v_attn,
                                 GI, W2H);
  k_gru<<<256, 256, 0, stream>>>(h0, W_hh, b_hh, GI, RNN, STEP);
  k_att<<<64, 1024, 0, stream>>>(enc, W2H, RNN, out_attn, CTX, out_hid);
  k_concat<<<1024, 256, 0, stream>>>(RNN, CTX, W_conc, b_conc, COT);
  k_out<<<625, 256, 0, stream>>>(COT, W_outp, b_outp, out);
}

// Round 10
// 541.708 us; speedup vs baseline: 1.0009x; 1.0009x over previous
//
#include <hip/hip_runtime.h>
#include <math.h>

// Problem constants
#define kH  1024
#define kB  64
#define kS  256
#define kV  10000
#define kH3 3072

typedef unsigned long long u64;

// ---------------- helpers ----------------
__device__ __forceinline__ float warp_sum(float v) {
#pragma unroll
  for (int off = 32; off > 0; off >>= 1) v += __shfl_down(v, off, 64);
  return v;  // valid on lane 0
}
__device__ __forceinline__ float warp_max_all(float v) {
#pragma unroll
  for (int off = 32; off > 0; off >>= 1) v = fmaxf(v, __shfl_xor(v, off, 64));
  return v;
}
__device__ __forceinline__ float warp_sum_all(float v) {
#pragma unroll
  for (int off = 32; off > 0; off >>= 1) v += __shfl_xor(v, off, 64);
  return v;
}
__device__ __forceinline__ float sigmoidf_(float x) {
  return __fdividef(1.0f, 1.0f + __expf(-x));
}
__device__ __forceinline__ float tanhf_(float x) {
  const float t = __expf(-2.0f * fabsf(x));
  const float r = __fdividef(1.0f - t, 1.0f + t);
  return copysignf(r, x);
}

// ======= Launch A: gi-GEMM (192 blocks) || w2h (256 blocks) ==============
__global__ __launch_bounds__(256) void k_pre(const int* __restrict__ seq,
    const float* __restrict__ emb, const float* __restrict__ W_ih,
    const float* __restrict__ b_ih, const float* __restrict__ W_attn,
    const float* __restrict__ v_attn, float* __restrict__ GI,
    float* __restrict__ w2h) {
  __shared__ float xl[64 * 65];   // X chunk, transposed [h][t], pad 65
  __shared__ float wl[16 * 64];   // W chunk, [r][h]
  __shared__ float4 red[256];     // w2h reduction
  const int tid = threadIdx.x;

  if (blockIdx.x < 192) {
    // ---- gi role: block owns 64t x 16r tile of GI = emb[seq] @ W_ih^T ----
    const int rblk = blockIdx.x * 16;
    const int t = tid & 63;       // lane = t (batch index)
    const int g = tid >> 6;       // wave = r-group (4 rows each)
    float acc[4] = {0.f, 0.f, 0.f, 0.f};

    for (int c = 0; c < 16; ++c) {
      const int h0 = c * 64;
      {
        const int tx = tid >> 2;
        const int tok = seq[tx];
        const float* xr = emb + (size_t)tok * kH + h0;
#pragma unroll
        for (int k = 0; k < 4; ++k) {
          const int slot = (tid & 3) + 4 * k;    // 0..15
          const float4 v = *(const float4*)(xr + slot * 4);
          const int hh = slot * 4;
          xl[(hh + 0) * 65 + tx] = v.x;
          xl[(hh + 1) * 65 + tx] = v.y;
          xl[(hh + 2) * 65 + tx] = v.z;
          xl[(hh + 3) * 65 + tx] = v.w;
        }
      }
      {
        const int r = tid >> 4, c4 = tid & 15;
        *(float4*)&wl[r * 64 + c4 * 4] =
            ((const float4*)(W_ih + (size_t)(rblk + r) * kH + h0))[c4];
      }
      __syncthreads();
#pragma unroll
      for (int q = 0; q < 16; ++q) {
        const int hh = q * 4;
        const float x0 = xl[(hh + 0) * 65 + t];
        const float x1 = xl[(hh + 1) * 65 + t];
        const float x2 = xl[(hh + 2) * 65 + t];
        const float x3 = xl[(hh + 3) * 65 + t];
#pragma unroll
        for (int i = 0; i < 4; ++i) {
          const float4 wq = *(const float4*)&wl[(g * 4 + i) * 64 + hh];
          acc[i] += wq.x * x0 + wq.y * x1 + wq.z * x2 + wq.w * x3;
        }
      }
      __syncthreads();
    }
    const float4 bi = *(const float4*)(b_ih + rblk + g * 4);
    float4 o;
    o.x = acc[0] + bi.x; o.y = acc[1] + bi.y;
    o.z = acc[2] + bi.z; o.w = acc[3] + bi.w;
    *(float4*)(GI + (size_t)t * kH3 + rblk + g * 4) = o;

  } else {
    // ---- w2h role: w2h[k] = sum_h v_attn[h]*W_attn[h][H+k] ----
    const int wb = blockIdx.x - 192;
    const int k0 = kH + wb * 4;
    float ax = 0, ay = 0, az = 0, aw = 0;
    for (int h = tid; h < kH; h += 256) {
      const float vh = v_attn[h];
      const float4 wq = *(const float4*)(W_attn + (size_t)h * 2048 + k0);
      ax += vh * wq.x; ay += vh * wq.y; az += vh * wq.z; aw += vh * wq.w;
    }
    red[tid] = make_float4(ax, ay, az, aw);
    __syncthreads();
    for (int s = 128; s > 0; s >>= 1) {
      if (tid < s) {
        const float4 a = red[tid], b = red[tid + s];
        red[tid] = make_float4(a.x + b.x, a.y + b.y, a.z + b.z, a.w + b.w);
      }
      __syncthreads();
    }
    if (tid == 0) *(float4*)(w2h + wb * 4) = red[0];
  }
}

// ---------------- Persistent GRU scan (64 sequential steps) ----------------
// R5 structure. Only change: lane0 stores rnnT[h][b] (transposed) instead of
// rnn[b][h] — downstream (concat lane=b streaming, hid strided read) wants
// column-major. NOTE: the GRU scans over the BATCH axis (t == b in the
// reference). 256 blocks x 256 threads, W_hh in LDS (48 KB), tagged-u64
// agent-scope atomic h-exchange (poison 0xAAAAAAAA never matches tags 1..64).
__global__ __launch_bounds__(256) void k_gru(const float* __restrict__ h0,
    const float* __restrict__ W_hh, const float* __restrict__ b_hh,
    const float* __restrict__ GI, float* __restrict__ rnnT,
    u64* __restrict__ step) {
  __shared__ float4 wlds4[12 * 256];      // 48 KB
  __shared__ __align__(16) float hs[2][kH];  // 8 KB double buffer
  const int tid  = threadIdx.x;
  const int lane = tid & 63;
  const int w    = tid >> 6;
  const int bid  = blockIdx.x;
  const int j    = bid * 4 + w;

#pragma unroll
  for (int c = 0; c < 12; ++c) {
    const int f    = c * 256 + tid;
    const int row  = f >> 8;
    const int col4 = f & 255;
    const int q    = row >> 2, r = row & 3;
    wlds4[f] = ((const float4*)(W_hh + ((size_t)q * kH + bid * 4 + r) * kH))[col4];
  }

  const float bhr = b_hh[j];
  const float bhz = b_hh[kH + j];
  const float bhn = b_hh[2 * kH + j];

  for (int t = 0; t < kB; ++t) {
    float gir = GI[(size_t)t * kH3 + j];
    float giz = GI[(size_t)t * kH3 + kH + j];
    float gin = GI[(size_t)t * kH3 + 2 * kH + j];
    asm volatile("" :: "v"(gir), "v"(giz), "v"(gin));

    float* hb = hs[t & 1];
    if (t == 0) {
      ((float4*)hb)[tid] = ((const float4*)h0)[tid];
    } else {
      const u64* sb = step + (size_t)(t - 1) * kH;
      const unsigned want = (unsigned)t;
      const int i0 = tid * 4;
      bool done[4] = {false, false, false, false};
      float v[4];
      while (true) {
        bool all = true;
#pragma unroll
        for (int k = 0; k < 4; ++k) {
          if (!done[k]) {
            const u64 x = __hip_atomic_load(&sb[i0 + k],
                __ATOMIC_RELAXED, __HIP_MEMORY_SCOPE_AGENT);
            if ((unsigned)(x >> 32) == want) {
              v[k] = __uint_as_float((unsigned)x);
              done[k] = true;
            } else {
              all = false;
            }
          }
        }
        if (all) break;
        __builtin_amdgcn_s_sleep(1);
      }
#pragma unroll
      for (int k = 0; k < 4; ++k) hb[i0 + k] = v[k];
    }
    __syncthreads();

    float4 hx4[4];
#pragma unroll
    for (int c = 0; c < 4; ++c) hx4[c] = ((const float4*)hb)[lane + 64 * c];

    float d[3];
#pragma unroll
    for (int q = 0; q < 3; ++q) {
      float acc = 0.f;
#pragma unroll
      for (int c = 0; c < 4; ++c) {
        const float4 wq = wlds4[(q * 4 + w) * 256 + lane + 64 * c];
        const float4 h4 = hx4[c];
        acc += wq.x * h4.x + wq.y * h4.y + wq.z * h4.z + wq.w * h4.w;
      }
      d[q] = acc;
    }
#pragma unroll
    for (int q = 0; q < 3; ++q) d[q] = warp_sum(d[q]);

    if (lane == 0) {
      const float ho = hb[j];
      const float r = sigmoidf_(gir + d[0] + bhr);
      const float z = sigmoidf_(giz + d[1] + bhz);
      const float n = tanhf_(gin + r * (d[2] + bhn));
      const float hn = (1.f - z) * n + z * ho;
      __hip_atomic_store(&step[(size_t)t * kH + j],
                         (((u64)(t + 1)) << 32) | __float_as_uint(hn),
                         __ATOMIC_RELAXED, __HIP_MEMORY_SCOPE_AGENT);
      rnnT[(size_t)j * kB + t] = hn;  // transposed [h][b] for downstream
    }
  }
}

// ====== scores: 256 blocks (b x s-quarter), 4-way-ILP dots ===============
// R9: k_att ran on 64 blocks = 64 CUs (75% chip idle) while streaming enc.
// Spread over 256 blocks; per-score dot order bit-identical to before.
__global__ __launch_bounds__(256) void k_sc(const float* __restrict__ enc,
    const float* __restrict__ w2h, float* __restrict__ sc) {
  const int tid = threadIdx.x;
  const int lane = tid & 63, w = tid >> 6;   // w: 0..3
  const int b = blockIdx.x & 63, q = blockIdx.x >> 6;  // q: 0..3
  const float4* wp = (const float4*)w2h + lane * 4;
  const float4 wq0 = wp[0], wq1 = wp[1], wq2 = wp[2], wq3 = wp[3];
  const int s0 = q * 64 + w * 16;
#pragma unroll
  for (int kb = 0; kb < 4; ++kb) {
    float acc[4];
#pragma unroll
    for (int i = 0; i < 4; ++i) {
      const int s = s0 + kb * 4 + i;
      const float4* ep =
          (const float4*)(enc + ((size_t)s * kB + b) * kH) + lane * 4;
      const float4 e0 = ep[0], e1 = ep[1], e2 = ep[2], e3 = ep[3];
      float a = e0.x*wq0.x + e0.y*wq0.y + e0.z*wq0.z + e0.w*wq0.w;
      a += e1.x*wq1.x + e1.y*wq1.y + e1.z*wq1.z + e1.w*wq1.w;
      a += e2.x*wq2.x + e2.y*wq2.y + e2.z*wq2.z + e2.w*wq2.w;
      a += e3.x*wq3.x + e3.y*wq3.y + e3.z*wq3.z + e3.w*wq3.w;
      acc[i] = a;
    }
#pragma unroll
    for (int i = 0; i < 4; ++i) acc[i] = warp_sum(acc[i]);
    if (lane == 0) {
#pragma unroll
      for (int i = 0; i < 4; ++i) sc[b * kS + s0 + kb * 4 + i] = acc[i];
    }
  }
}

// ====== softmax (64 blocks) + hid copy ===================================
__global__ __launch_bounds__(256) void k_sm(const float* __restrict__ sc,
    const float* __restrict__ rnnT, float* __restrict__ attn,
    float* __restrict__ hid) {
  __shared__ float sm[4], ss[4];
  const int b = blockIdx.x, t = threadIdx.x, lane = t & 63, w = t >> 6;
  const float x = sc[b * kS + t];
  float m = warp_max_all(x);
  if (lane == 0) sm[w] = m;
  __syncthreads();
  m = fmaxf(fmaxf(sm[0], sm[1]), fmaxf(sm[2], sm[3]));
  const float e = __expf(x - m);
  float s = warp_sum_all(e);
  if (lane == 0) ss[w] = s;
  __syncthreads();
  s = ss[0] + ss[1] + ss[2] + ss[3];
  attn[b * kS + t] = e / s;
  if (b < 4) {  // hid[i] = h_final[i], i = b*256+t (strided rnnT read, tiny)
    hid[b * kS + t] = rnnT[(size_t)(b * kS + t) * kB + 63];
  }
}

// ====== context partials, TRANSPOSED store PARTT[ch][h][b] ===============
// Same math/order as R5's k_context; only the store layout changed so the
// downstream sum & concat read coalesced with lane=b.
__global__ __launch_bounds__(256) void k_ctx(const float* __restrict__ enc,
    const float* __restrict__ attn, float* __restrict__ partT) {
  const int b  = blockIdx.x & 63;
  const int ch = blockIdx.x >> 6;
  const int h0 = threadIdx.x * 4;
  float ax = 0, ay = 0, az = 0, aw = 0;
  const int s0 = ch * 64;
#pragma unroll 4
  for (int s = s0; s < s0 + 64; ++s) {
    const float a = attn[b * kS + s];
    const float4 v = *(const float4*)(enc + ((size_t)s * kB + b) * kH + h0);
    ax += a * v.x; ay += a * v.y; az += a * v.z; aw += a * v.w;
  }
  float* base = partT + (size_t)ch * (kH * kB);
  base[(h0 + 0) * kB + b] = ax;
  base[(h0 + 1) * kB + b] = ay;
  base[(h0 + 2) * kB + b] = az;
  base[(h0 + 3) * kB + b] = aw;
}

// ====== ctxT[h][b] = sum_ch PARTT[ch][h][b]  (fully coalesced) ===========
__global__ __launch_bounds__(256) void k_ctxsum(const float* __restrict__ partT,
    float* __restrict__ ctxT) {
  const int e = blockIdx.x * 256 + threadIdx.x;  // 0..65535
  const float p0 = partT[e];
  const float p1 = partT[65536 + e];
  const float p2 = partT[131072 + e];
  const float p3 = partT[196608 + e];
  ctxT[e] = p0 + p1 + p2 + p3;
}

// ====== coT[i][b] = tanh([rnn,ctx][b] . W_concat[i] + b_c[i]) ============
// R9 rewrite: lane = b. Wave (i, h-half) streams h sequentially: W_c via
// wave-uniform s_loads, x via coalesced 256B rnnT/ctxT reads. No shuffles,
// no redundant row gathers (old version: 512 MB of strided L2 gathers +
// 6-shfl reduce per output). 256 blocks x 512 threads = 2048 waves.
__global__ __launch_bounds__(512) void k_concat(const float* __restrict__ rnnT,
    const float* __restrict__ ctxT, const float* __restrict__ W_c,
    const float* __restrict__ b_c, float* __restrict__ coT) {
  __shared__ float sred[8 * 64];
  const int tid = threadIdx.x;
  const int lane = tid & 63;          // = b
  const int g = tid >> 6;             // wave 0..7
  const int half = g & 1;
  const int i = __builtin_amdgcn_readfirstlane(blockIdx.x * 4 + (g >> 1));
  const float* wr = W_c + (size_t)i * 2048;
  const int hb = half * 512;

  float a0 = 0.f, a1 = 0.f, a2 = 0.f, a3 = 0.f;
  // rnn part: h in [hb, hb+512)
#pragma unroll 4
  for (int h = hb; h < hb + 512; h += 4) {
    const float4 wq = *(const float4*)(wr + h);
    a0 += wq.x * rnnT[(size_t)(h + 0) * kB + lane];
    a1 += wq.y * rnnT[(size_t)(h + 1) * kB + lane];
    a2 += wq.z * rnnT[(size_t)(h + 2) * kB + lane];
    a3 += wq.w * rnnT[(size_t)(h + 3) * kB + lane];
  }
  // ctx part: h2 in [hb, hb+512)
#pragma unroll 4
  for (int h = hb; h < hb + 512; h += 4) {
    const float4 wq = *(const float4*)(wr + kH + h);
    a0 += wq.x * ctxT[(size_t)(h + 0) * kB + lane];
    a1 += wq.y * ctxT[(size_t)(h + 1) * kB + lane];
    a2 += wq.z * ctxT[(size_t)(h + 2) * kB + lane];
    a3 += wq.w * ctxT[(size_t)(h + 3) * kB + lane];
  }
  sred[g * 64 + lane] = ((a0 + a1) + (a2 + a3));
  __syncthreads();
  if (half == 0) {
    const float tot = sred[g * 64 + lane] + sred[(g + 1) * 64 + lane];
    coT[(size_t)i * kB + lane] = tanhf(tot + b_c[i]);
  }
}

// ====== out[b][v] = coT[:,b] . W_out[v] + b_out[v] =======================
__global__ __launch_bounds__(256) void k_out(const float* __restrict__ coT,
    const float* __restrict__ W_out, const float* __restrict__ b_out,
    float* __restrict__ out) {
  __shared__ float wlds[16 * kH];  // 64 KB
  const int v0 = blockIdx.x * 16;
  {
    const float4* src = (const float4*)(W_out + (size_t)v0 * kH);
    float4 tmp[16];
#pragma unroll
    for (int c = 0; c < 16; ++c) tmp[c] = src[threadIdx.x + 256 * c];
    float4* dst = (float4*)wlds;
#pragma unroll
    for (int c = 0; c < 16; ++c) dst[threadIdx.x + 256 * c] = tmp[c];
  }
  __syncthreads();

  const int lane = threadIdx.x & 63;   // = b
  const int w    = threadIdx.x >> 6;   // wave: v-rows 4w..4w+3
  float acc[4] = {0.f, 0.f, 0.f, 0.f};
#pragma unroll 2
  for (int h = 0; h < kH; h += 4) {
    const float x0 = coT[(size_t)(h + 0) * kB + lane];
    const float x1 = coT[(size_t)(h + 1) * kB + lane];
    const float x2 = coT[(size_t)(h + 2) * kB + lane];
    const float x3 = coT[(size_t)(h + 3) * kB + lane];
#pragma unroll
    for (int vi = 0; vi < 4; ++vi) {
      const float4 wq = *(const float4*)&wlds[(w * 4 + vi) * kH + h];
      acc[vi] += wq.x * x0 + wq.y * x1 + wq.z * x2 + wq.w * x3;
    }
  }
  const float4 bq = *(const float4*)(b_out + v0 + w * 4);
  float4 r;
  r.x = acc[0] + bq.x; r.y = acc[1] + bq.y;
  r.z = acc[2] + bq.z; r.w = acc[3] + bq.w;
  *(float4*)&out[(size_t)lane * kV + v0 + w * 4] = r;
}

// ---------------- launcher ----------------
extern "C" void kernel_launch(void* const* d_in, const int* in_sizes, int n_in,
                              void* d_out, int out_size, void* d_ws,
                              size_t ws_size, hipStream_t stream) {
  const int*   seq    = (const int*)  d_in[0];
  const float* h0     = (const float*)d_in[1];
  const float* enc    = (const float*)d_in[2];
  const float* emb    = (const float*)d_in[3];
  const float* W_ih   = (const float*)d_in[4];
  const float* W_hh   = (const float*)d_in[5];
  const float* b_ih   = (const float*)d_in[6];
  const float* b_hh   = (const float*)d_in[7];
  const float* W_attn = (const float*)d_in[8];
  // d_in[9] = b_attn: drops out of softmax (shift invariance)
  const float* v_attn = (const float*)d_in[10];
  const float* W_conc = (const float*)d_in[11];
  const float* b_conc = (const float*)d_in[12];
  const float* W_outp = (const float*)d_in[13];
  const float* b_outp = (const float*)d_in[14];

  float* out      = (float*)d_out;           // (B,V) = 640000
  float* out_hid  = out + 640000;            // (1,1,H) = 1024
  float* out_attn = out + 641024;            // (B,1,S) = 16384

  float* ws = (float*)d_ws;
  float* GI    = ws;                     // 64*3072      = 196608
  float* RNNT  = ws + 196608;            // 1024*64      =  65536
  u64*   STEP  = (u64*)(ws + 262144);    // 64*1024 u64  = 131072 floats
  float* W2H   = ws + 393216;            // 1024
  float* SC    = ws + 394240;            // 64*256       =  16384
  float* PARTT = ws + 410624;            // 4*1024*64    = 262144
  float* CTXT  = ws + 672768;            // 1024*64      =  65536
  float* COT   = ws + 738304;            // 1024*64      =  65536 (end 803840)

  k_pre<<<448, 256, 0, stream>>>(seq, emb, W_ih, b_ih, W_attn, v_attn,
                                 GI, W2H);
  k_gru<<<256, 256, 0, stream>>>(h0, W_hh, b_hh, GI, RNNT, STEP);
  k_sc<<<256, 256, 0, stream>>>(enc, W2H, SC);
  k_sm<<<64, 256, 0, stream>>>(SC, RNNT, out_attn, out_hid);
  k_ctx<<<256, 256, 0, stream>>>(enc, out_attn, PARTT);
  k_ctxsum<<<256, 256, 0, stream>>>(PARTT, CTXT);
  k_concat<<<256, 512, 0, stream>>>(RNNT, CTXT, W_conc, b_conc, COT);
  k_out<<<625, 256, 0, stream>>>(COT, W_outp, b_outp, out);
}